// Round 5
// baseline (204.959 us; speedup 1.0000x reference)
//
#include <hip/hip_runtime.h>
#include <hip/hip_cooperative_groups.h>
#include <stdint.h>

namespace cg = cooperative_groups;
typedef unsigned long long u64;

#define NNODE 4096
#define NG    8
#define M     512      // nodes per graph
#define W     8        // 64-bit words per 512-bit mask

// workspace layout (bytes)
#define OFF_MASK 0                         // u64[4096][8]     = 262144 B
#define OFF_DEG  (262144)                  // float[4096]      =  16384 B
#define OFF_F1   (262144 + 16384)          // float[4096]      =  16384 B
#define OFF_FEAT (262144 + 32768)          // float[8][7][512] = 114688 B

static __device__ __forceinline__ u64 shfl_xor_u64(u64 v, int mask) {
    return ((u64)(unsigned)__shfl_xor((int)(v >> 32), mask, 64) << 32) |
           (u64)(unsigned)__shfl_xor((int)(v & 0xffffffffu), mask, 64);
}

// ---------------------------------------------------------------------------
// Single cooperative kernel, 256 blocks x 256 threads, grid.sync() between
// phases. Phase bodies are identical to the verified R4 split kernels.
//   A: pack   (256 blocks, 16 rows each)
//   B: feat   (blocks 0..63 = graph x chunk, 4 threads/node)
//   C: f3     (blocks 0..7 = graph)
//   D: stats  (blocks 0..111 = (g,f,half))
// ---------------------------------------------------------------------------
__global__ __launch_bounds__(256) void k_fused(const float* __restrict__ A,
                                               float* __restrict__ out,
                                               char* __restrict__ ws) {
    u64*   gmask = (u64*)(ws + OFF_MASK);
    float* gdeg  = (float*)(ws + OFF_DEG);
    float* f1g   = (float*)(ws + OFF_F1);
    float* featg = (float*)(ws + OFF_FEAT);

    cg::grid_group grid = cg::this_grid();
    int b = blockIdx.x, t = threadIdx.x;
    int wv = t >> 6, lane = t & 63;

    __shared__ __align__(16) u64 smT[W * M];     // 32 KB (phase B)
    __shared__ float sdeg[M];
    __shared__ u64 planes[9][W];
    __shared__ __align__(16) float sv[M];        // phase C (f1s) / phase D
    __shared__ double rsum[4], r2s[4], r3s[4], r4s[4];
    __shared__ double smean;

    // ---- Phase A: pack rows [16b, 16b+16); wave wv does 4 rows.
#pragma unroll
    for (int k = 0; k < 4; k++) {
        int row = b * 16 + wv * 4 + k;
        int lo  = (row >> 9) << 9;
        const float* rowp = A + (size_t)row * NNODE + lo;
        float4 a = *(const float4*)(rowp + lane * 8);
        float4 c4 = *(const float4*)(rowp + lane * 8 + 4);
        unsigned int byte =
            (a.x  != 0.f ? 1u : 0u) | (a.y  != 0.f ? 2u : 0u) |
            (a.z  != 0.f ? 4u : 0u) | (a.w  != 0.f ? 8u : 0u) |
            (c4.x != 0.f ? 16u : 0u) | (c4.y != 0.f ? 32u : 0u) |
            (c4.z != 0.f ? 64u : 0u) | (c4.w != 0.f ? 128u : 0u);
        ((unsigned char*)gmask)[(size_t)row * 64 + lane] = (unsigned char)byte;
        int c = __popc(byte);
#pragma unroll
        for (int off = 32; off; off >>= 1) c += __shfl_down(c, off, 64);
        if (lane == 0) gdeg[row] = (float)c;
    }
    grid.sync();

    // ---- Phase B: sparse ego features (blocks 0..63).
    if (b < 64) {
        int g = b >> 3, chunk = b & 7;
        const u64* gm = gmask + (size_t)g * M * W;
        for (int idx = t; idx < M * W; idx += 256) {
            int u = idx >> 3, w = idx & 7;
            smT[w * M + u] = gm[idx];               // coalesced global read
        }
        for (int i = t; i < M; i += 256) sdeg[i] = gdeg[g * M + i];
        __syncthreads();

        for (int w = wv; w < W; w += 4) {           // wave wv: words wv, wv+4
            int d = (int)sdeg[(w << 6) + lane];
#pragma unroll
            for (int k = 0; k < 9; k++) {
                u64 bal = __ballot(((d >> k) & 1) != 0);
                if (lane == 0) planes[k][w] = bal;
            }
        }
        __syncthreads();

        int nl = t >> 2, q = t & 3;                 // node-in-chunk, word-pair
        int n  = chunk * 64 + nl;
        u64 m1[W], reach[W];
#pragma unroll
        for (int w = 0; w < W; w++) { m1[w] = smT[w * M + n]; reach[w] = 0ull; }
        m1[n >> 6] |= 1ull << (n & 63);             // M1 = A | I

        int f4 = 0;
#pragma unroll
        for (int wq = 0; wq < 2; wq++) {
            int w = 2 * q + wq;
            u64 bits = m1[w];
            while (bits) {                           // sparse: u in ego1(n)
                int bb = __ffsll(bits) - 1;
                bits &= bits - 1;
                int u = (w << 6) + bb;
#pragma unroll
                for (int w2 = 0; w2 < W; w2++) {
                    u64 r = smT[w2 * M + u];
                    reach[w2] |= r;                  // B>0 mask (A symmetric)
                    f4 += __popcll(r & m1[w2]);      // edges ego1 -> ego1
                }
            }
        }
        f4 += __shfl_xor(f4, 1, 64);
        f4 += __shfl_xor(f4, 2, 64);
#pragma unroll
        for (int w = 0; w < W; w++) {
            reach[w] |= shfl_xor_u64(reach[w], 1);
            reach[w] |= shfl_xor_u64(reach[w], 2);
        }

        if (q == 0) {
            int f6c = 0;
            u64 m2m[W];
#pragma unroll
            for (int w = 0; w < W; w++) { m2m[w] = m1[w] | reach[w]; f6c += __popcll(m2m[w]); }
            int f5i = 0, f2i = 0;
            u64 selfb = 1ull << (n & 63);
#pragma unroll
            for (int k = 0; k < 9; k++) {
                int c5 = 0, c2 = 0;
#pragma unroll
                for (int w = 0; w < W; w++) {
                    u64 ar = (w == (n >> 6)) ? (m1[w] & ~selfb) : m1[w];
                    c5 += __popcll(m2m[w] & planes[k][w]);   // M2 @ deg
                    c2 += __popcll(ar & planes[k][w]);       // A  @ deg
                }
                f5i += c5 << k;
                f2i += c2 << k;
            }
            float deg = sdeg[n];
            float f4raw = (float)f4;
            float f1 = (deg > 1.f) ? 2.f * (f4raw - deg) / (deg * (deg - 1.f)) : 0.f;
            float* fb = featg + (size_t)g * 7 * M;
            fb[0 * M + n] = deg;
            fb[1 * M + n] = f1;
            fb[2 * M + n] = (deg > 0.f) ? (float)f2i / deg : 0.f;
            fb[4 * M + n] = f4raw * 0.5f;
            fb[5 * M + n] = (float)f5i - 2.f * f4raw;
            fb[6 * M + n] = (float)f6c - deg - 1.f;
            f1g[g * M + n] = f1;
        }
    }
    grid.sync();

    // ---- Phase C: f3 = neighbor mean of f1 (blocks 0..7, 2 nodes/thread).
    if (b < NG) {
        int g = b;
        sv[t]       = f1g[g * M + t];
        sv[t + 256] = f1g[g * M + t + 256];
        __syncthreads();
#pragma unroll
        for (int h = 0; h < 2; h++) {
            int n = h * 256 + t;
            const u64* m = gmask + ((size_t)g * M + n) * W;
            float sum = 0.f;
#pragma unroll
            for (int w = 0; w < W; w++) {
                u64 bits = m[w];                     // A row (no self bit)
                while (bits) {
                    int bb = __ffsll(bits) - 1;
                    bits &= bits - 1;
                    sum += sv[(w << 6) + bb];
                }
            }
            float deg = gdeg[g * M + n];
            featg[(size_t)g * 7 * M + 3 * M + n] = (deg > 0.f) ? sum / deg : 0.f;
        }
    }
    grid.sync();

    // ---- Phase D: stats (blocks 0..111 = (g,f,half)).
    if (b < NG * 7 * 2) {
        int gf = b >> 1, half = b & 1;
        int g = gf / 7, f = gf % 7;

        sv[t]       = featg[(size_t)gf * M + t];
        sv[t + 256] = featg[(size_t)gf * M + t + 256];
        __syncthreads();

        if (half == 0) {                 // moments only once per (g,f)
            double s = (double)sv[t] + (double)sv[t + 256];
#pragma unroll
            for (int off = 32; off; off >>= 1) s += __shfl_xor(s, off, 64);
            if (lane == 0) rsum[wv] = s;
            __syncthreads();
            if (t == 0) smean = (rsum[0] + rsum[1] + rsum[2] + rsum[3]) * (1.0 / 512.0);
            __syncthreads();
            double mean = smean;
            double c1 = (double)sv[t] - mean, c2v = (double)sv[t + 256] - mean;
            double a2 = c1 * c1, b2 = c2v * c2v;
            double p2 = a2 + b2, p3 = a2 * c1 + b2 * c2v, p4 = a2 * a2 + b2 * b2;
#pragma unroll
            for (int off = 32; off; off >>= 1) {
                p2 += __shfl_xor(p2, off, 64);
                p3 += __shfl_xor(p3, off, 64);
                p4 += __shfl_xor(p4, off, 64);
            }
            if (lane == 0) { r2s[wv] = p2; r3s[wv] = p3; r4s[wv] = p4; }
            __syncthreads();
            if (t == 0) {
                double m2 = (r2s[0] + r2s[1] + r2s[2] + r2s[3]) * (1.0 / 512.0);
                double m3 = (r3s[0] + r3s[1] + r3s[2] + r3s[3]) * (1.0 / 512.0);
                double m4 = (r4s[0] + r4s[1] + r4s[2] + r4s[3]) * (1.0 / 512.0);
                double sd = sqrt(m2);
                double den3 = m2 * sd;  if (den3 < 1e-4) den3 = 1e-4;
                double den4 = m2 * m2;  if (den4 < 1e-4) den4 = 1e-4;
                out[g * 35 + f]      = (float)smean;
                out[g * 35 + 14 + f] = (float)sd;
                out[g * 35 + 21 + f] = (float)(m3 / den3);
                out[g * 35 + 28 + f] = (float)(m4 / den4);
            }
        }

        // median: lower-middle element = rank 255 (torch.median semantics)
        float cv = sv[half * 256 + t];
        int less = 0, eq = 0;
        for (int j = 0; j < M; j += 4) {
            float4 x = *(const float4*)&sv[j];       // wave-uniform => broadcast
            less += (x.x < cv) + (x.y < cv) + (x.z < cv) + (x.w < cv);
            eq   += (x.x == cv) + (x.y == cv) + (x.z == cv) + (x.w == cv);
        }
        if (less <= 255 && less + eq > 255) out[g * 35 + 7 + f] = cv;
    }
}

extern "C" void kernel_launch(void* const* d_in, const int* in_sizes, int n_in,
                              void* d_out, int out_size, void* d_ws, size_t ws_size,
                              hipStream_t stream) {
    const float* A = (const float*)d_in[0];   // [4096,4096] fp32, block-diagonal 0/1
    float* out = (float*)d_out;               // [8,35] fp32
    char* ws = (char*)d_ws;

    void* args[] = { (void*)&A, (void*)&out, (void*)&ws };
    hipLaunchCooperativeKernel((const void*)k_fused, dim3(256), dim3(256),
                               args, 0, stream);
}

// Round 6
// 129.098 us; speedup vs baseline: 1.5876x; 1.5876x over previous
//
#include <hip/hip_runtime.h>
#include <stdint.h>

typedef unsigned long long u64;

#define NNODE 4096
#define NG    8
#define M     512      // nodes per graph
#define W     8        // 64-bit words per 512-bit mask

// workspace layout (bytes)
#define OFF_MASK 0                         // u64[4096][8]     = 262144 B
#define OFF_DEG  (262144)                  // float[4096]      =  16384 B
#define OFF_F1   (262144 + 16384)          // float[4096]      =  16384 B
#define OFF_FEAT (262144 + 32768)          // float[8][7][512] = 114688 B

static __device__ __forceinline__ u64 shfl_xor_u64(u64 v, int mask) {
    return ((u64)(unsigned)__shfl_xor((int)(v >> 32), mask, 64) << 32) |
           (u64)(unsigned)__shfl_xor((int)(v & 0xffffffffu), mask, 64);
}

// ---------------------------------------------------------------------------
// Kernel 1: pack + sparse ego features fused. Block = (graph, 64-node chunk).
// Each block packs its graph's full 512x512 0/1 diagonal block from A into
// LDS bitmasks (dup reads across the 8 chunks of a graph hit L2/L3), then
// runs the verified feat body (4 threads/node). Chunk-0 blocks export
// gmask/gdeg for kernel 2's f3 path.
// ---------------------------------------------------------------------------
__global__ __launch_bounds__(256) void k_feat2(const float* __restrict__ A,
                                               float* __restrict__ featg,
                                               float* __restrict__ f1g,
                                               u64* __restrict__ gmask,
                                               float* __restrict__ gdeg) {
    int g = blockIdx.x >> 3, chunk = blockIdx.x & 7;
    int t = threadIdx.x;
    int wv = t >> 6, lane = t & 63;

    __shared__ __align__(16) u64 smT[W * M];    // [w][node], 32 KB
    __shared__ float sdeg[M];
    __shared__ u64 planes[9][W];

    // ---- pack: wave wv packs rows [128*wv, 128*wv+128); lane l -> cols 8l..8l+7
    const float* Ab = A + (size_t)(g * M) * NNODE + g * M;
#pragma unroll 4
    for (int k = 0; k < 128; k++) {
        int r = wv * 128 + k;
        const float* rowp = Ab + (size_t)r * NNODE;
        float4 a  = *(const float4*)(rowp + lane * 8);
        float4 c4 = *(const float4*)(rowp + lane * 8 + 4);
        unsigned int byte =
            (a.x  != 0.f ? 1u : 0u) | (a.y  != 0.f ? 2u : 0u) |
            (a.z  != 0.f ? 4u : 0u) | (a.w  != 0.f ? 8u : 0u) |
            (c4.x != 0.f ? 16u : 0u) | (c4.y != 0.f ? 32u : 0u) |
            (c4.z != 0.f ? 64u : 0u) | (c4.w != 0.f ? 128u : 0u);
        ((unsigned char*)smT)[(((size_t)(lane >> 3) * M + r) << 3) | (lane & 7)] =
            (unsigned char)byte;
    }
    __syncthreads();

    // ---- degrees by popcount (2 nodes/thread); chunk 0 exports gdeg
#pragma unroll
    for (int h = 0; h < 2; h++) {
        int n = h * 256 + t;
        int d = 0;
#pragma unroll
        for (int w = 0; w < W; w++) d += __popcll(smT[w * M + n]);
        sdeg[n] = (float)d;
        if (chunk == 0) gdeg[g * M + n] = (float)d;
    }
    __syncthreads();

    // ---- degree bit-planes (wave wv builds words wv, wv+4)
    for (int w = wv; w < W; w += 4) {
        int d = (int)sdeg[(w << 6) + lane];
#pragma unroll
        for (int k = 0; k < 9; k++) {
            u64 bal = __ballot(((d >> k) & 1) != 0);
            if (lane == 0) planes[k][w] = bal;
        }
    }
    // ---- chunk 0 exports gmask in node-major layout for kernel 2's f3
    if (chunk == 0) {
        for (int idx = t; idx < M * W; idx += 256) {
            int n = idx >> 3, w = idx & 7;
            gmask[((size_t)g * M + n) * W + w] = smT[w * M + n];
        }
    }
    __syncthreads();

    // ---- feat body (verified R4): 4 threads/node, thread q scans words 2q,2q+1
    int nl = t >> 2, q = t & 3;
    int n  = chunk * 64 + nl;
    u64 m1[W], reach[W];
#pragma unroll
    for (int w = 0; w < W; w++) { m1[w] = smT[w * M + n]; reach[w] = 0ull; }
    m1[n >> 6] |= 1ull << (n & 63);             // M1 = A | I

    int f4 = 0;
#pragma unroll
    for (int wq = 0; wq < 2; wq++) {
        int w = 2 * q + wq;
        u64 bits = m1[w];
        while (bits) {                           // sparse: u in ego1(n)
            int bb = __ffsll(bits) - 1;
            bits &= bits - 1;
            int u = (w << 6) + bb;
#pragma unroll
            for (int w2 = 0; w2 < W; w2++) {
                u64 r = smT[w2 * M + u];
                reach[w2] |= r;                  // B>0 mask (A symmetric)
                f4 += __popcll(r & m1[w2]);      // edges ego1 -> ego1
            }
        }
    }
    f4 += __shfl_xor(f4, 1, 64);
    f4 += __shfl_xor(f4, 2, 64);
#pragma unroll
    for (int w = 0; w < W; w++) {
        reach[w] |= shfl_xor_u64(reach[w], 1);
        reach[w] |= shfl_xor_u64(reach[w], 2);
    }

    if (q == 0) {
        int f6c = 0;
        u64 m2m[W];
#pragma unroll
        for (int w = 0; w < W; w++) { m2m[w] = m1[w] | reach[w]; f6c += __popcll(m2m[w]); }
        int f5i = 0, f2i = 0;
        u64 selfb = 1ull << (n & 63);
#pragma unroll
        for (int k = 0; k < 9; k++) {
            int c5 = 0, c2 = 0;
#pragma unroll
            for (int w = 0; w < W; w++) {
                u64 ar = (w == (n >> 6)) ? (m1[w] & ~selfb) : m1[w];  // A row
                c5 += __popcll(m2m[w] & planes[k][w]);   // M2 @ deg, bit-sliced
                c2 += __popcll(ar & planes[k][w]);       // A  @ deg, bit-sliced
            }
            f5i += c5 << k;
            f2i += c2 << k;
        }
        float deg = sdeg[n];
        float f4raw = (float)f4;
        float f1 = (deg > 1.f) ? 2.f * (f4raw - deg) / (deg * (deg - 1.f)) : 0.f;
        float* fb = featg + (size_t)g * 7 * M;
        fb[0 * M + n] = deg;
        fb[1 * M + n] = f1;
        fb[2 * M + n] = (deg > 0.f) ? (float)f2i / deg : 0.f;
        fb[4 * M + n] = f4raw * 0.5f;
        fb[5 * M + n] = (float)f5i - 2.f * f4raw;
        fb[6 * M + n] = (float)f6c - deg - 1.f;
        f1g[g * M + n] = f1;
    }
}

// ---------------------------------------------------------------------------
// Kernel 2: f3 (inline, for f==3 blocks) + per-(g,f) statistics.
// Block = (g, f, candidate-half); 112 blocks. Stats body verified in R4.
// ---------------------------------------------------------------------------
__global__ __launch_bounds__(256) void k_stats2(const float* __restrict__ featg,
                                                const float* __restrict__ f1g,
                                                const u64* __restrict__ gmask,
                                                const float* __restrict__ gdeg,
                                                float* __restrict__ out) {
    int blk = blockIdx.x;            // 0..111
    int gf = blk >> 1, half = blk & 1;
    int g = gf / 7, f = gf % 7;
    int t = threadIdx.x;
    __shared__ __align__(16) float sv[M];
    __shared__ float f1s[M];
    __shared__ double rsum[4], r2[4], r3[4], r4[4];
    __shared__ double smean;

    if (f == 3) {                    // compute f3 = neighbor mean of f1 locally
        f1s[t]       = f1g[g * M + t];
        f1s[t + 256] = f1g[g * M + t + 256];
        __syncthreads();
#pragma unroll
        for (int h = 0; h < 2; h++) {
            int n = h * 256 + t;
            const u64* m = gmask + ((size_t)g * M + n) * W;
            float sum = 0.f;
#pragma unroll
            for (int w = 0; w < W; w++) {
                u64 bits = m[w];                 // A row (no self bit)
                while (bits) {
                    int bb = __ffsll(bits) - 1;
                    bits &= bits - 1;
                    sum += f1s[(w << 6) + bb];
                }
            }
            float deg = gdeg[g * M + n];
            sv[n] = (deg > 0.f) ? sum / deg : 0.f;
        }
        __syncthreads();
    } else {
        sv[t]       = featg[(size_t)gf * M + t];
        sv[t + 256] = featg[(size_t)gf * M + t + 256];
        __syncthreads();
    }

    int wv = t >> 6, lane = t & 63;
    if (half == 0) {                 // moments only once per (g,f)
        double s = (double)sv[t] + (double)sv[t + 256];
#pragma unroll
        for (int off = 32; off; off >>= 1) s += __shfl_xor(s, off, 64);
        if (lane == 0) rsum[wv] = s;
        __syncthreads();
        if (t == 0) smean = (rsum[0] + rsum[1] + rsum[2] + rsum[3]) * (1.0 / 512.0);
        __syncthreads();
        double mean = smean;
        double c1 = (double)sv[t] - mean, c2v = (double)sv[t + 256] - mean;
        double a2 = c1 * c1, b2 = c2v * c2v;
        double p2 = a2 + b2, p3 = a2 * c1 + b2 * c2v, p4 = a2 * a2 + b2 * b2;
#pragma unroll
        for (int off = 32; off; off >>= 1) {
            p2 += __shfl_xor(p2, off, 64);
            p3 += __shfl_xor(p3, off, 64);
            p4 += __shfl_xor(p4, off, 64);
        }
        if (lane == 0) { r2[wv] = p2; r3[wv] = p3; r4[wv] = p4; }
        __syncthreads();
        if (t == 0) {
            double m2 = (r2[0] + r2[1] + r2[2] + r2[3]) * (1.0 / 512.0);
            double m3 = (r3[0] + r3[1] + r3[2] + r3[3]) * (1.0 / 512.0);
            double m4 = (r4[0] + r4[1] + r4[2] + r4[3]) * (1.0 / 512.0);
            double sd = sqrt(m2);
            double den3 = m2 * sd;  if (den3 < 1e-4) den3 = 1e-4;
            double den4 = m2 * m2;  if (den4 < 1e-4) den4 = 1e-4;
            out[g * 35 + f]      = (float)smean;
            out[g * 35 + 14 + f] = (float)sd;
            out[g * 35 + 21 + f] = (float)(m3 / den3);
            out[g * 35 + 28 + f] = (float)(m4 / den4);
        }
    }

    // median: lower-middle element = rank 255 (torch.median semantics)
    float cv = sv[half * 256 + t];
    int less = 0, eq = 0;
    for (int j = 0; j < M; j += 4) {
        float4 x = *(const float4*)&sv[j];       // wave-uniform => broadcast
        less += (x.x < cv) + (x.y < cv) + (x.z < cv) + (x.w < cv);
        eq   += (x.x == cv) + (x.y == cv) + (x.z == cv) + (x.w == cv);
    }
    if (less <= 255 && less + eq > 255) out[g * 35 + 7 + f] = cv;
}

extern "C" void kernel_launch(void* const* d_in, const int* in_sizes, int n_in,
                              void* d_out, int out_size, void* d_ws, size_t ws_size,
                              hipStream_t stream) {
    const float* A = (const float*)d_in[0];   // [4096,4096] fp32, block-diagonal 0/1
    float* out = (float*)d_out;               // [8,35] fp32
    char* ws = (char*)d_ws;
    u64*   gmask = (u64*)(ws + OFF_MASK);
    float* gdeg  = (float*)(ws + OFF_DEG);
    float* f1g   = (float*)(ws + OFF_F1);
    float* featg = (float*)(ws + OFF_FEAT);

    k_feat2 <<<NG * 8,    256, 0, stream>>>(A, featg, f1g, gmask, gdeg);
    k_stats2<<<NG * 7 * 2, 256, 0, stream>>>(featg, f1g, gmask, gdeg, out);
}

// Round 7
// 114.601 us; speedup vs baseline: 1.7885x; 1.1265x over previous
//
#include <hip/hip_runtime.h>
#include <stdint.h>

typedef unsigned long long u64;

#define NNODE 4096
#define NG    8
#define M     512      // nodes per graph
#define W     8        // 64-bit words per 512-bit mask

// workspace layout (bytes)
#define OFF_MASK 0                         // u64[4096][8]     = 262144 B
#define OFF_DEG  (262144)                  // float[4096]      =  16384 B
#define OFF_F1   (262144 + 16384)          // float[4096]      =  16384 B
#define OFF_FEAT (262144 + 32768)          // float[8][7][512] = 114688 B

// ---------------------------------------------------------------------------
// Kernel 1: pack diagonal-block adjacency rows into 512-bit masks + degrees.
// One wave per row; lane l covers columns [8l, 8l+8) of the block.
// (verified R1/R2/R4)
// ---------------------------------------------------------------------------
__global__ __launch_bounds__(256) void k_pack(const float* __restrict__ A,
                                              u64* __restrict__ gmask,
                                              float* __restrict__ gdeg) {
    int row  = (blockIdx.x << 2) + (threadIdx.x >> 6);  // 0..4095
    int lane = threadIdx.x & 63;
    int lo   = (row >> 9) << 9;                         // block column base
    const float* rowp = A + (size_t)row * NNODE + lo;
    float4 a = *(const float4*)(rowp + lane * 8);
    float4 b = *(const float4*)(rowp + lane * 8 + 4);
    unsigned int byte =
        (a.x != 0.f ? 1u : 0u) | (a.y != 0.f ? 2u : 0u) |
        (a.z != 0.f ? 4u : 0u) | (a.w != 0.f ? 8u : 0u) |
        (b.x != 0.f ? 16u : 0u) | (b.y != 0.f ? 32u : 0u) |
        (b.z != 0.f ? 64u : 0u) | (b.w != 0.f ? 128u : 0u);
    ((unsigned char*)gmask)[(size_t)row * 64 + lane] = (unsigned char)byte;
    int c = __popc(byte);
#pragma unroll
    for (int off = 32; off; off >>= 1) c += __shfl_down(c, off, 64);
    if (lane == 0) gdeg[row] = (float)c;
}

static __device__ __forceinline__ u64 shfl_xor_u64(u64 v, int mask) {
    return ((u64)(unsigned)__shfl_xor((int)(v >> 32), mask, 64) << 32) |
           (u64)(unsigned)__shfl_xor((int)(v & 0xffffffffu), mask, 64);
}

// ---------------------------------------------------------------------------
// Kernel 2: sparse ego-net features. Block = (graph, 64-node chunk) -> 64
// blocks, 4 threads per node. (verified R4)
// ---------------------------------------------------------------------------
__global__ __launch_bounds__(256) void k_feat(const u64* __restrict__ gmask,
                                              const float* __restrict__ gdeg,
                                              float* __restrict__ featg,
                                              float* __restrict__ f1g) {
    int g = blockIdx.x >> 3, chunk = blockIdx.x & 7;
    int t = threadIdx.x;
    __shared__ u64 smT[W * M];      // transposed [w][node], 32 KB
    __shared__ float sdeg[M];
    __shared__ u64 planes[9][W];    // degree bit-planes

    const u64* gm = gmask + (size_t)g * M * W;
    for (int idx = t; idx < M * W; idx += 256) {
        int u = idx >> 3, w = idx & 7;
        smT[w * M + u] = gm[idx];               // coalesced global read
    }
    for (int i = t; i < M; i += 256) sdeg[i] = gdeg[g * M + i];
    __syncthreads();

    int wv = t >> 6, lane = t & 63;
    for (int w = wv; w < W; w += 4) {           // wave wv builds words wv, wv+4
        int d = (int)sdeg[(w << 6) + lane];
#pragma unroll
        for (int k = 0; k < 9; k++) {
            u64 bal = __ballot(((d >> k) & 1) != 0);
            if (lane == 0) planes[k][w] = bal;
        }
    }
    __syncthreads();

    int nl = t >> 2, q = t & 3;                 // node-in-chunk, word-pair id
    int n  = chunk * 64 + nl;
    u64 m1[W], reach[W];
#pragma unroll
    for (int w = 0; w < W; w++) { m1[w] = smT[w * M + n]; reach[w] = 0ull; }
    m1[n >> 6] |= 1ull << (n & 63);             // M1 = A | I

    int f4 = 0;
#pragma unroll
    for (int wq = 0; wq < 2; wq++) {
        int w = 2 * q + wq;
        u64 bits = m1[w];
        while (bits) {                           // sparse: u in ego1(n)
            int bb = __ffsll(bits) - 1;
            bits &= bits - 1;
            int u = (w << 6) + bb;
#pragma unroll
            for (int w2 = 0; w2 < W; w2++) {
                u64 r = smT[w2 * M + u];
                reach[w2] |= r;                  // B>0 mask (A symmetric)
                f4 += __popcll(r & m1[w2]);      // edges ego1 -> ego1
            }
        }
    }
    f4 += __shfl_xor(f4, 1, 64);
    f4 += __shfl_xor(f4, 2, 64);
#pragma unroll
    for (int w = 0; w < W; w++) {
        reach[w] |= shfl_xor_u64(reach[w], 1);
        reach[w] |= shfl_xor_u64(reach[w], 2);
    }

    if (q == 0) {
        int f6c = 0;
        u64 m2m[W];
#pragma unroll
        for (int w = 0; w < W; w++) { m2m[w] = m1[w] | reach[w]; f6c += __popcll(m2m[w]); }
        int f5i = 0, f2i = 0;
        u64 selfb = 1ull << (n & 63);
#pragma unroll
        for (int k = 0; k < 9; k++) {
            int c5 = 0, c2 = 0;
#pragma unroll
            for (int w = 0; w < W; w++) {
                u64 ar = (w == (n >> 6)) ? (m1[w] & ~selfb) : m1[w];  // A row
                c5 += __popcll(m2m[w] & planes[k][w]);   // M2 @ deg, bit-sliced
                c2 += __popcll(ar & planes[k][w]);       // A  @ deg, bit-sliced
            }
            f5i += c5 << k;
            f2i += c2 << k;
        }
        float deg = sdeg[n];
        float f4raw = (float)f4;
        float f1 = (deg > 1.f) ? 2.f * (f4raw - deg) / (deg * (deg - 1.f)) : 0.f;
        float* fb = featg + (size_t)g * 7 * M;
        fb[0 * M + n] = deg;
        fb[1 * M + n] = f1;
        fb[2 * M + n] = (deg > 0.f) ? (float)f2i / deg : 0.f;
        fb[4 * M + n] = f4raw * 0.5f;
        fb[5 * M + n] = (float)f5i - 2.f * f4raw;
        fb[6 * M + n] = (float)f6c - deg - 1.f;
        f1g[g * M + n] = f1;
    }
}

// ---------------------------------------------------------------------------
// Kernel 3: f3 (inline, for f==3 blocks) + per-(g,f) statistics.
// Block = (g, f, candidate-half); 112 blocks. (verified R6)
// ---------------------------------------------------------------------------
__global__ __launch_bounds__(256) void k_stats2(const float* __restrict__ featg,
                                                const float* __restrict__ f1g,
                                                const u64* __restrict__ gmask,
                                                const float* __restrict__ gdeg,
                                                float* __restrict__ out) {
    int blk = blockIdx.x;            // 0..111
    int gf = blk >> 1, half = blk & 1;
    int g = gf / 7, f = gf % 7;
    int t = threadIdx.x;
    __shared__ __align__(16) float sv[M];
    __shared__ float f1s[M];
    __shared__ double rsum[4], r2[4], r3[4], r4[4];
    __shared__ double smean;

    if (f == 3) {                    // compute f3 = neighbor mean of f1 locally
        f1s[t]       = f1g[g * M + t];
        f1s[t + 256] = f1g[g * M + t + 256];
        __syncthreads();
#pragma unroll
        for (int h = 0; h < 2; h++) {
            int n = h * 256 + t;
            const u64* m = gmask + ((size_t)g * M + n) * W;
            float sum = 0.f;
#pragma unroll
            for (int w = 0; w < W; w++) {
                u64 bits = m[w];                 // A row (no self bit)
                while (bits) {
                    int bb = __ffsll(bits) - 1;
                    bits &= bits - 1;
                    sum += f1s[(w << 6) + bb];
                }
            }
            float deg = gdeg[g * M + n];
            sv[n] = (deg > 0.f) ? sum / deg : 0.f;
        }
        __syncthreads();
    } else {
        sv[t]       = featg[(size_t)gf * M + t];
        sv[t + 256] = featg[(size_t)gf * M + t + 256];
        __syncthreads();
    }

    int wv = t >> 6, lane = t & 63;
    if (half == 0) {                 // moments only once per (g,f)
        double s = (double)sv[t] + (double)sv[t + 256];
#pragma unroll
        for (int off = 32; off; off >>= 1) s += __shfl_xor(s, off, 64);
        if (lane == 0) rsum[wv] = s;
        __syncthreads();
        if (t == 0) smean = (rsum[0] + rsum[1] + rsum[2] + rsum[3]) * (1.0 / 512.0);
        __syncthreads();
        double mean = smean;
        double c1 = (double)sv[t] - mean, c2v = (double)sv[t + 256] - mean;
        double a2 = c1 * c1, b2 = c2v * c2v;
        double p2 = a2 + b2, p3 = a2 * c1 + b2 * c2v, p4 = a2 * a2 + b2 * b2;
#pragma unroll
        for (int off = 32; off; off >>= 1) {
            p2 += __shfl_xor(p2, off, 64);
            p3 += __shfl_xor(p3, off, 64);
            p4 += __shfl_xor(p4, off, 64);
        }
        if (lane == 0) { r2[wv] = p2; r3[wv] = p3; r4[wv] = p4; }
        __syncthreads();
        if (t == 0) {
            double m2 = (r2[0] + r2[1] + r2[2] + r2[3]) * (1.0 / 512.0);
            double m3 = (r3[0] + r3[1] + r3[2] + r3[3]) * (1.0 / 512.0);
            double m4 = (r4[0] + r4[1] + r4[2] + r4[3]) * (1.0 / 512.0);
            double sd = sqrt(m2);
            double den3 = m2 * sd;  if (den3 < 1e-4) den3 = 1e-4;
            double den4 = m2 * m2;  if (den4 < 1e-4) den4 = 1e-4;
            out[g * 35 + f]      = (float)smean;
            out[g * 35 + 14 + f] = (float)sd;
            out[g * 35 + 21 + f] = (float)(m3 / den3);
            out[g * 35 + 28 + f] = (float)(m4 / den4);
        }
    }

    // median: lower-middle element = rank 255 (torch.median semantics)
    float cv = sv[half * 256 + t];
    int less = 0, eq = 0;
    for (int j = 0; j < M; j += 4) {
        float4 x = *(const float4*)&sv[j];       // wave-uniform => broadcast
        less += (x.x < cv) + (x.y < cv) + (x.z < cv) + (x.w < cv);
        eq   += (x.x == cv) + (x.y == cv) + (x.z == cv) + (x.w == cv);
    }
    if (less <= 255 && less + eq > 255) out[g * 35 + 7 + f] = cv;
}

extern "C" void kernel_launch(void* const* d_in, const int* in_sizes, int n_in,
                              void* d_out, int out_size, void* d_ws, size_t ws_size,
                              hipStream_t stream) {
    const float* A = (const float*)d_in[0];   // [4096,4096] fp32, block-diagonal 0/1
    float* out = (float*)d_out;               // [8,35] fp32
    char* ws = (char*)d_ws;
    u64*   gmask = (u64*)(ws + OFF_MASK);
    float* gdeg  = (float*)(ws + OFF_DEG);
    float* f1g   = (float*)(ws + OFF_F1);
    float* featg = (float*)(ws + OFF_FEAT);

    k_pack  <<<NNODE / 4,  256, 0, stream>>>(A, gmask, gdeg);
    k_feat  <<<NG * 8,     256, 0, stream>>>(gmask, gdeg, featg, f1g);
    k_stats2<<<NG * 7 * 2, 256, 0, stream>>>(featg, f1g, gmask, gdeg, out);
}